// Round 2
// baseline (315.305 us; speedup 1.0000x reference)
//
#include <hip/hip_runtime.h>
#include <hip/hip_bf16.h>
#include <math.h>

#define BB 16
#define COUTC 64
#define HH 256
#define WWD 256
#define NBLK (BB*HH)          // 4096 blocks for kernel1
#define NPIX (BB*HH*WWD)      // 1,048,576 pixels

typedef __attribute__((ext_vector_type(8))) short short8;
typedef __attribute__((ext_vector_type(4))) float f32x4;

__device__ __forceinline__ unsigned short f2bf(float f) {
    __hip_bfloat16 h = __float2bfloat16(f);
    return __builtin_bit_cast(unsigned short, h);
}

// ---------------------------------------------------------------------------
// Kernel 1: offset conv + deformable sampling (VALU, fp32) + fused
// [256px x 54] @ [54 x 64ch] matmul on MFMA (bf16 in / fp32 accum).
// One block per (b,h) row; thread = w. Writes y to out, per-block per-channel
// sum/sumsq partials to psum/psq (deterministic reduction order).
// ---------------------------------------------------------------------------
__global__ __launch_bounds__(256) void dcn_fused_kernel(
    const float* __restrict__ x,
    const float* __restrict__ w_off,
    const float* __restrict__ b_off,
    const float* __restrict__ w_dcn,
    const float* __restrict__ w_conv,
    const float* __restrict__ b_conv,
    float* __restrict__ out,
    float* __restrict__ psum,     // [64][NBLK]
    float* __restrict__ psq)      // [64][NBLK]
{
    // LDS plan (40960 B total -> 4 blocks/CU):
    //   [0,32768)      kbuf: A-matrix bf16 [256px][64k], 128B rows, 16B-chunk
    //                  XOR swizzle (chunk ^= px&7). Reused as ybuf (fp32
    //                  [16ch][260px]) in the epilogue.
    //   [32768,40960)  wT: bf16 [64n][64k], same swizzle. Reused for the
    //                  cross-wave stat scratch in the epilogue.
    __shared__ __align__(16) char smem[40960];
    char* kbp = smem;
    char* wtp = smem + 32768;

    const int tid = threadIdx.x;
    const int b = blockIdx.x >> 8;
    const int h = blockIdx.x & 255;
    const int w = tid;
    const int l   = tid & 63;     // lane
    const int wv  = tid >> 6;     // wave 0..3 (owns px 64*wv..64*wv+63)
    const int g   = l >> 4;       // lane group 0..3
    const int r15 = l & 15;

    const float* xb = x + (size_t)b * (3*HH*WWD);

    // --- build wT[n][k] bf16 (combined w_dcn | w_conv | zeros), swizzled ---
    {
        const int n = tid >> 2, kb0 = (tid & 3) * 16;
        unsigned short tmp[16];
        #pragma unroll
        for (int j = 0; j < 16; ++j) {
            int k = kb0 + j;
            float v = 0.f;
            if (k < 27)      v = w_dcn[n*27 + k];
            else if (k < 54) v = w_conv[n*27 + (k - 27)];
            tmp[j] = f2bf(v);
        }
        #pragma unroll
        for (int c = 0; c < 2; ++c) {
            int chunk = (kb0 >> 3) + c;
            uint4 v;
            v.x = (unsigned)tmp[c*8+0] | ((unsigned)tmp[c*8+1] << 16);
            v.y = (unsigned)tmp[c*8+2] | ((unsigned)tmp[c*8+3] << 16);
            v.z = (unsigned)tmp[c*8+4] | ((unsigned)tmp[c*8+5] << 16);
            v.w = (unsigned)tmp[c*8+6] | ((unsigned)tmp[c*8+7] << 16);
            *(uint4*)(wtp + n*128 + ((chunk ^ (n & 7)) << 4)) = v;
        }
    }

    // --- 3x3 zero-padded neighborhood, 3 channels (fp32) ------------------
    float xn[3][3][3];
    #pragma unroll
    for (int c = 0; c < 3; ++c) {
        #pragma unroll
        for (int dy = 0; dy < 3; ++dy) {
            int yy = h + dy - 1;
            #pragma unroll
            for (int dx = 0; dx < 3; ++dx) {
                int xx = w + dx - 1;
                bool ok = (yy >= 0) && (yy < HH) && (xx >= 0) && (xx < WWD);
                xn[c][dy][dx] = ok ? xb[c*(HH*WWD) + yy*WWD + xx] : 0.f;
            }
        }
    }

    // --- offset conv: 18 channels (weights wave-uniform -> s_load) --------
    float off[18];
    #pragma unroll
    for (int j = 0; j < 18; ++j) off[j] = b_off[j];
    #pragma unroll
    for (int c = 0; c < 3; ++c)
        #pragma unroll
        for (int ky = 0; ky < 3; ++ky)
            #pragma unroll
            for (int kx = 0; kx < 3; ++kx) {
                float v = xn[c][ky][kx];
                #pragma unroll
                for (int j = 0; j < 18; ++j)
                    off[j] = fmaf(v, w_off[((j*3 + c)*3 + ky)*3 + kx], off[j]);
            }

    // --- deformable bilinear taps: taps[k][c] (fp32) ----------------------
    float taps[9][3];
    #pragma unroll
    for (int k = 0; k < 9; ++k) {
        const int ky = k / 3, kx = k % 3;
        float py = (float)(h + ky - 1) + off[2*k];
        float px = (float)(w + kx - 1) + off[2*k + 1];
        float y0f = floorf(py), x0f = floorf(px);
        float ly = py - y0f, lx = px - x0f;
        float hy = 1.f - ly, hx = 1.f - lx;
        int y0 = (int)y0f, x0 = (int)x0f;
        int y1 = y0 + 1,  x1 = x0 + 1;
        bool vy0 = (y0 >= 0) && (y0 < HH);
        bool vy1 = (y1 >= 0) && (y1 < HH);
        bool vx0 = (x0 >= 0) && (x0 < WWD);
        bool vx1 = (x1 >= 0) && (x1 < WWD);
        float w00 = (vy0 && vx0) ? hy*hx : 0.f;
        float w01 = (vy0 && vx1) ? hy*lx : 0.f;
        float w10 = (vy1 && vx0) ? ly*hx : 0.f;
        float w11 = (vy1 && vx1) ? ly*lx : 0.f;
        int yc0 = min(max(y0, 0), HH-1),  yc1 = min(max(y1, 0), HH-1);
        int xc0 = min(max(x0, 0), WWD-1), xc1 = min(max(x1, 0), WWD-1);
        int i00 = yc0*WWD + xc0, i01 = yc0*WWD + xc1;
        int i10 = yc1*WWD + xc0, i11 = yc1*WWD + xc1;
        #pragma unroll
        for (int c = 0; c < 3; ++c) {
            const float* xc = xb + c*(HH*WWD);
            taps[k][c] = w00*xc[i00] + w01*xc[i01] + w10*xc[i10] + w11*xc[i11];
        }
    }

    // --- pack per-pixel K-vector to bf16, write swizzled row to kbuf ------
    {
        unsigned short u[64];
        #pragma unroll
        for (int c = 0; c < 3; ++c)
            #pragma unroll
            for (int kt = 0; kt < 9; ++kt)
                u[c*9 + kt] = f2bf(taps[kt][c]);
        #pragma unroll
        for (int c = 0; c < 3; ++c)
            #pragma unroll
            for (int ky = 0; ky < 3; ++ky)
                #pragma unroll
                for (int kx = 0; kx < 3; ++kx)
                    u[27 + c*9 + ky*3 + kx] = f2bf(xn[c][ky][kx]);
        #pragma unroll
        for (int k = 54; k < 64; ++k) u[k] = 0;
        #pragma unroll
        for (int c8 = 0; c8 < 8; ++c8) {
            uint4 v;
            v.x = (unsigned)u[c8*8+0] | ((unsigned)u[c8*8+1] << 16);
            v.y = (unsigned)u[c8*8+2] | ((unsigned)u[c8*8+3] << 16);
            v.z = (unsigned)u[c8*8+4] | ((unsigned)u[c8*8+5] << 16);
            v.w = (unsigned)u[c8*8+6] | ((unsigned)u[c8*8+7] << 16);
            *(uint4*)(kbp + w*128 + ((c8 ^ (w & 7)) << 4)) = v;
        }
    }

    __syncthreads();

    // --- MFMA: D[64px x 64ch] per wave, 16x16x32 bf16 ---------------------
    short8 bfr[2][4];
    #pragma unroll
    for (int ks = 0; ks < 2; ++ks)
        #pragma unroll
        for (int nt = 0; nt < 4; ++nt) {
            int n = nt*16 + r15;
            int chunk = ks*4 + g;
            bfr[ks][nt] = *(const short8*)(wtp + n*128 + ((chunk ^ (n & 7)) << 4));
        }

    f32x4 acc[4][4];
    #pragma unroll
    for (int mt = 0; mt < 4; ++mt)
        #pragma unroll
        for (int nt = 0; nt < 4; ++nt)
            acc[mt][nt] = (f32x4){0.f, 0.f, 0.f, 0.f};

    #pragma unroll
    for (int ks = 0; ks < 2; ++ks)
        #pragma unroll
        for (int mt = 0; mt < 4; ++mt) {
            int row = wv*64 + mt*16 + r15;
            int chunk = ks*4 + g;
            short8 a = *(const short8*)(kbp + row*128 + ((chunk ^ (row & 7)) << 4));
            #pragma unroll
            for (int nt = 0; nt < 4; ++nt)
                acc[mt][nt] = __builtin_amdgcn_mfma_f32_16x16x32_bf16(
                    a, bfr[ks][nt], acc[mt][nt], 0, 0, 0);
        }

    __syncthreads();   // kbuf reads done; safe to reuse as ybuf

    // --- epilogue: per N-tile, bias + stats (from regs) + coalesced store -
    float* ybuf = (float*)kbp;          // [16ch][260px] fp32
    float* l2s  = (float*)wtp;          // [4wv][16ch]
    float* l2q  = (float*)(wtp + 256);

    #pragma unroll 1
    for (int nt = 0; nt < 4; ++nt) {
        float bcv = b_conv[nt*16 + r15];
        float s = 0.f, s2 = 0.f;
        #pragma unroll
        for (int mt = 0; mt < 4; ++mt) {
            f32x4 v = acc[mt][nt];
            float4 o;
            o.x = v.x + bcv; o.y = v.y + bcv; o.z = v.z + bcv; o.w = v.w + bcv;
            s += o.x + o.y + o.z + o.w;
            s2 = fmaf(o.x, o.x, s2); s2 = fmaf(o.y, o.y, s2);
            s2 = fmaf(o.z, o.z, s2); s2 = fmaf(o.w, o.w, s2);
            // D layout: ch = nt*16 + r15, px = wv*64 + mt*16 + g*4 + reg
            *(float4*)(ybuf + r15*260 + wv*64 + mt*16 + g*4) = o;
        }
        // lanes l, l^16, l^32, l^48 share ch -> deterministic shuffle reduce
        s  += __shfl_xor(s, 16);  s  += __shfl_xor(s, 32);
        s2 += __shfl_xor(s2, 16); s2 += __shfl_xor(s2, 32);
        if (l < 16) { l2s[wv*16 + l] = s; l2q[wv*16 + l] = s2; }
        __syncthreads();

        size_t obase = ((size_t)(b*64 + nt*16) << 16) + (size_t)h*256 + tid;
        #pragma unroll
        for (int i = 0; i < 16; ++i)
            out[obase + ((size_t)i << 16)] = ybuf[i*260 + tid];

        if (tid < 16) {
            float ts  = l2s[tid] + l2s[16+tid] + l2s[32+tid] + l2s[48+tid];
            float tq  = l2q[tid] + l2q[16+tid] + l2q[32+tid] + l2q[48+tid];
            psum[(nt*16 + tid)*NBLK + blockIdx.x] = ts;
            psq [(nt*16 + tid)*NBLK + blockIdx.x] = tq;
        }
        __syncthreads();
    }
}

// ---------------------------------------------------------------------------
// Kernel 2: reduce partials -> per-channel scale/shift (deterministic order)
// ---------------------------------------------------------------------------
__global__ __launch_bounds__(256) void bn_stats_kernel(
    const float* __restrict__ psum,
    const float* __restrict__ psq,
    const float* __restrict__ gamma,
    const float* __restrict__ beta,
    float* __restrict__ ss)       // [0..63]=scale, [64..127]=shift
{
    __shared__ float rs[256], rq[256];
    const int ch = blockIdx.x, tid = threadIdx.x;
    float s = 0.f, s2 = 0.f;
    for (int j = tid; j < NBLK; j += 256) {
        s  += psum[ch*NBLK + j];
        s2 += psq [ch*NBLK + j];
    }
    rs[tid] = s; rq[tid] = s2;
    __syncthreads();
    for (int st = 128; st > 0; st >>= 1) {
        if (tid < st) { rs[tid] += rs[tid + st]; rq[tid] += rq[tid + st]; }
        __syncthreads();
    }
    if (tid == 0) {
        const float N = (float)NPIX;
        float mean = rs[0] / N;
        float var  = rq[0] / N - mean*mean;
        float rstd = rsqrtf(var + 1e-5f);
        float sc   = gamma[ch] * rstd;
        ss[ch]      = sc;
        ss[64 + ch] = beta[ch] - mean * sc;
    }
}

// ---------------------------------------------------------------------------
// Kernel 3: in-place affine + SiLU over d_out (float4, memory-bound)
// ---------------------------------------------------------------------------
__global__ __launch_bounds__(256) void bn_silu_kernel(
    float* __restrict__ y,
    const float* __restrict__ ss)
{
    __shared__ float sc[64], sh[64];
    if (threadIdx.x < 64) {
        sc[threadIdx.x] = ss[threadIdx.x];
        sh[threadIdx.x] = ss[64 + threadIdx.x];
    }
    __syncthreads();
    float4* y4 = (float4*)y;
    const int total4 = (BB*COUTC*HH*WWD) / 4;   // 16,777,216
    for (int i = blockIdx.x*256 + threadIdx.x; i < total4; i += gridDim.x*256) {
        float4 v = y4[i];
        const int o = (i >> 14) & 63;           // element_idx>>16 & 63
        const float a = sc[o], t = sh[o];
        float z;
        z = fmaf(v.x, a, t); v.x = z / (1.f + __expf(-z));
        z = fmaf(v.y, a, t); v.y = z / (1.f + __expf(-z));
        z = fmaf(v.z, a, t); v.z = z / (1.f + __expf(-z));
        z = fmaf(v.w, a, t); v.w = z / (1.f + __expf(-z));
        y4[i] = v;
    }
}

// ---------------------------------------------------------------------------
extern "C" void kernel_launch(void* const* d_in, const int* in_sizes, int n_in,
                              void* d_out, int out_size, void* d_ws, size_t ws_size,
                              hipStream_t stream) {
    const float* x      = (const float*)d_in[0];
    const float* w_off  = (const float*)d_in[1];
    const float* b_off  = (const float*)d_in[2];
    const float* w_dcn  = (const float*)d_in[3];
    const float* w_conv = (const float*)d_in[4];
    const float* b_conv = (const float*)d_in[5];
    const float* gamma  = (const float*)d_in[6];
    const float* beta   = (const float*)d_in[7];
    float* out = (float*)d_out;

    float* psum = (float*)d_ws;                    // 64*4096
    float* psq  = psum + 64*NBLK;                  // 64*4096
    float* ss   = psq  + 64*NBLK;                  // 128 floats

    dcn_fused_kernel<<<NBLK, 256, 0, stream>>>(x, w_off, b_off, w_dcn, w_conv,
                                               b_conv, out, psum, psq);
    bn_stats_kernel<<<64, 256, 0, stream>>>(psum, psq, gamma, beta, ss);
    bn_silu_kernel<<<2048, 256, 0, stream>>>(out, ss);
}

// Round 3
// 234.971 us; speedup vs baseline: 1.3419x; 1.3419x over previous
//
#include <hip/hip_runtime.h>
#include <hip/hip_bf16.h>
#include <math.h>

#define BB 16
#define COUTC 64
#define HH 256
#define WWD 256
#define NBLK (BB*HH)          // 4096 blocks for kernel1
#define NPIX (BB*HH*WWD)      // 1,048,576 pixels
#define YTOT ((size_t)NPIX*COUTC)   // 67,108,864 y elements

typedef __attribute__((ext_vector_type(8))) short short8;
typedef __attribute__((ext_vector_type(4))) float f32x4;
typedef __attribute__((ext_vector_type(4))) unsigned short us4;
typedef __attribute__((ext_vector_type(8))) unsigned short us8;

__device__ __forceinline__ unsigned short f2bf(float f) {
    __hip_bfloat16 h = __float2bfloat16(f);
    return __builtin_bit_cast(unsigned short, h);
}
__device__ __forceinline__ float bf2f(unsigned short u) {
    unsigned v = (unsigned)u << 16;
    return __builtin_bit_cast(float, v);
}

// ---------------------------------------------------------------------------
// Kernel 1: offset conv + deformable sampling (VALU, fp32) + fused
// [256px x 54] @ [54 x 64ch] matmul on MFMA (bf16 in / fp32 accum).
// One block per (b,h) row; thread = w. Epilogue FULLY UNROLLED (acc must stay
// in registers — runtime nt indexing spilled 256B/thread to scratch in R2).
// Writes y (bf16 to ws, or fp32 to out in fallback) + per-block stats.
// ---------------------------------------------------------------------------
template<bool BF16Y>
__global__ __launch_bounds__(256) void dcn_fused_kernel(
    const float* __restrict__ x,
    const float* __restrict__ w_off,
    const float* __restrict__ b_off,
    const float* __restrict__ w_dcn,
    const float* __restrict__ w_conv,
    const float* __restrict__ b_conv,
    float* __restrict__ outf,
    unsigned short* __restrict__ yws,
    float* __restrict__ psum,     // [64][NBLK]
    float* __restrict__ psq)      // [64][NBLK]
{
    // LDS (40960 B -> 4 blocks/CU):
    //   [0,32768)      kbuf: A bf16 [256px][64k], 128B rows, 16B-chunk XOR
    //                  swizzle (chunk ^= px&7) -> conflict-free ds_read_b128.
    //   [32768,40960)  wT: bf16 [64n][64k], same swizzle. Reused (behind the
    //                  post-MFMA barrier) as stats scratch [4wv][64ch] x2.
    __shared__ __align__(16) char smem[40960];
    char* kbp = smem;
    char* wtp = smem + 32768;

    const int tid = threadIdx.x;
    const int b = blockIdx.x >> 8;
    const int h = blockIdx.x & 255;
    const int w = tid;
    const int l   = tid & 63;     // lane
    const int wv  = tid >> 6;     // wave 0..3 (owns px 64*wv..64*wv+63)
    const int g   = l >> 4;       // lane group 0..3
    const int r15 = l & 15;

    const float* xb = x + (size_t)b * (3*HH*WWD);

    // --- build wT[n][k] bf16 (w_dcn | w_conv | zeros), swizzled -----------
    {
        const int n = tid >> 2, kb0 = (tid & 3) * 16;
        unsigned short tmp[16];
        #pragma unroll
        for (int j = 0; j < 16; ++j) {
            int k = kb0 + j;
            float v = 0.f;
            if (k < 27)      v = w_dcn[n*27 + k];
            else if (k < 54) v = w_conv[n*27 + (k - 27)];
            tmp[j] = f2bf(v);
        }
        #pragma unroll
        for (int c = 0; c < 2; ++c) {
            int chunk = (kb0 >> 3) + c;
            uint4 v;
            v.x = (unsigned)tmp[c*8+0] | ((unsigned)tmp[c*8+1] << 16);
            v.y = (unsigned)tmp[c*8+2] | ((unsigned)tmp[c*8+3] << 16);
            v.z = (unsigned)tmp[c*8+4] | ((unsigned)tmp[c*8+5] << 16);
            v.w = (unsigned)tmp[c*8+6] | ((unsigned)tmp[c*8+7] << 16);
            *(uint4*)(wtp + n*128 + ((chunk ^ (n & 7)) << 4)) = v;
        }
    }

    // --- 3x3 zero-padded neighborhood, 3 channels (fp32) ------------------
    float xn[3][3][3];
    #pragma unroll
    for (int c = 0; c < 3; ++c) {
        #pragma unroll
        for (int dy = 0; dy < 3; ++dy) {
            int yy = h + dy - 1;
            #pragma unroll
            for (int dx = 0; dx < 3; ++dx) {
                int xx = w + dx - 1;
                bool ok = (yy >= 0) && (yy < HH) && (xx >= 0) && (xx < WWD);
                xn[c][dy][dx] = ok ? xb[c*(HH*WWD) + yy*WWD + xx] : 0.f;
            }
        }
    }

    // --- offset conv: 18 channels (weights wave-uniform -> s_load) --------
    float off[18];
    #pragma unroll
    for (int j = 0; j < 18; ++j) off[j] = b_off[j];
    #pragma unroll
    for (int c = 0; c < 3; ++c)
        #pragma unroll
        for (int ky = 0; ky < 3; ++ky)
            #pragma unroll
            for (int kx = 0; kx < 3; ++kx) {
                float v = xn[c][ky][kx];
                #pragma unroll
                for (int j = 0; j < 18; ++j)
                    off[j] = fmaf(v, w_off[((j*3 + c)*3 + ky)*3 + kx], off[j]);
            }

    // --- deformable bilinear taps: taps[k][c] (fp32) ----------------------
    float taps[9][3];
    #pragma unroll
    for (int k = 0; k < 9; ++k) {
        const int ky = k / 3, kx = k % 3;
        float py = (float)(h + ky - 1) + off[2*k];
        float px = (float)(w + kx - 1) + off[2*k + 1];
        float y0f = floorf(py), x0f = floorf(px);
        float ly = py - y0f, lx = px - x0f;
        float hy = 1.f - ly, hx = 1.f - lx;
        int y0 = (int)y0f, x0 = (int)x0f;
        int y1 = y0 + 1,  x1 = x0 + 1;
        bool vy0 = (y0 >= 0) && (y0 < HH);
        bool vy1 = (y1 >= 0) && (y1 < HH);
        bool vx0 = (x0 >= 0) && (x0 < WWD);
        bool vx1 = (x1 >= 0) && (x1 < WWD);
        float w00 = (vy0 && vx0) ? hy*hx : 0.f;
        float w01 = (vy0 && vx1) ? hy*lx : 0.f;
        float w10 = (vy1 && vx0) ? ly*hx : 0.f;
        float w11 = (vy1 && vx1) ? ly*lx : 0.f;
        int yc0 = min(max(y0, 0), HH-1),  yc1 = min(max(y1, 0), HH-1);
        int xc0 = min(max(x0, 0), WWD-1), xc1 = min(max(x1, 0), WWD-1);
        int i00 = yc0*WWD + xc0, i01 = yc0*WWD + xc1;
        int i10 = yc1*WWD + xc0, i11 = yc1*WWD + xc1;
        #pragma unroll
        for (int c = 0; c < 3; ++c) {
            const float* xc = xb + c*(HH*WWD);
            taps[k][c] = w00*xc[i00] + w01*xc[i01] + w10*xc[i10] + w11*xc[i11];
        }
    }

    // --- pack per-pixel K-vector to bf16, write swizzled row to kbuf ------
    {
        unsigned short u[64];
        #pragma unroll
        for (int c = 0; c < 3; ++c)
            #pragma unroll
            for (int kt = 0; kt < 9; ++kt)
                u[c*9 + kt] = f2bf(taps[kt][c]);
        #pragma unroll
        for (int c = 0; c < 3; ++c)
            #pragma unroll
            for (int ky = 0; ky < 3; ++ky)
                #pragma unroll
                for (int kx = 0; kx < 3; ++kx)
                    u[27 + c*9 + ky*3 + kx] = f2bf(xn[c][ky][kx]);
        #pragma unroll
        for (int k = 54; k < 64; ++k) u[k] = 0;
        #pragma unroll
        for (int c8 = 0; c8 < 8; ++c8) {
            uint4 v;
            v.x = (unsigned)u[c8*8+0] | ((unsigned)u[c8*8+1] << 16);
            v.y = (unsigned)u[c8*8+2] | ((unsigned)u[c8*8+3] << 16);
            v.z = (unsigned)u[c8*8+4] | ((unsigned)u[c8*8+5] << 16);
            v.w = (unsigned)u[c8*8+6] | ((unsigned)u[c8*8+7] << 16);
            *(uint4*)(kbp + w*128 + ((c8 ^ (w & 7)) << 4)) = v;
        }
    }

    __syncthreads();

    // --- MFMA: D[64px x 64ch] per wave, 16x16x32 bf16 ---------------------
    short8 bfr[2][4];
    #pragma unroll
    for (int ks = 0; ks < 2; ++ks)
        #pragma unroll
        for (int nt = 0; nt < 4; ++nt) {
            int n = nt*16 + r15;
            int chunk = ks*4 + g;
            bfr[ks][nt] = *(const short8*)(wtp + n*128 + ((chunk ^ (n & 7)) << 4));
        }

    f32x4 acc[4][4];
    #pragma unroll
    for (int mt = 0; mt < 4; ++mt)
        #pragma unroll
        for (int nt = 0; nt < 4; ++nt)
            acc[mt][nt] = (f32x4){0.f, 0.f, 0.f, 0.f};

    #pragma unroll
    for (int ks = 0; ks < 2; ++ks)
        #pragma unroll
        for (int mt = 0; mt < 4; ++mt) {
            int row = wv*64 + mt*16 + r15;
            int chunk = ks*4 + g;
            short8 a = *(const short8*)(kbp + row*128 + ((chunk ^ (row & 7)) << 4));
            #pragma unroll
            for (int nt = 0; nt < 4; ++nt)
                acc[mt][nt] = __builtin_amdgcn_mfma_f32_16x16x32_bf16(
                    a, bfr[ks][nt], acc[mt][nt], 0, 0, 0);
        }

    __syncthreads();   // all kbuf/wT reads done -> wtp reusable as scratch

    // --- epilogue (FULLY unrolled): bias + stats + direct stores ----------
    float* l2s = (float*)wtp;           // [4wv][64ch]
    float* l2q = (float*)(wtp + 1024);  // [4wv][64ch]

    #pragma unroll
    for (int nt = 0; nt < 4; ++nt) {
        const float bcv = b_conv[nt*16 + r15];
        float s = 0.f, s2 = 0.f;
        // D layout: ch = nt*16 + r15, px = wv*64 + mt*16 + g*4 + reg
        const size_t base = ((size_t)(b*64 + nt*16 + r15) << 16)
                          + (size_t)h*256 + wv*64 + g*4;
        #pragma unroll
        for (int mt = 0; mt < 4; ++mt) {
            f32x4 v = acc[mt][nt];
            float ox = v.x + bcv, oy = v.y + bcv, oz = v.z + bcv, ow = v.w + bcv;
            s += ox + oy + oz + ow;
            s2 = fmaf(ox, ox, s2); s2 = fmaf(oy, oy, s2);
            s2 = fmaf(oz, oz, s2); s2 = fmaf(ow, ow, s2);
            if (BF16Y) {
                us4 pv = { f2bf(ox), f2bf(oy), f2bf(oz), f2bf(ow) };
                *(us4*)(yws + base + mt*16) = pv;
            } else {
                float4 pv = { ox, oy, oz, ow };
                *(float4*)(outf + base + mt*16) = pv;
            }
        }
        // lanes l, l^16, l^32, l^48 share ch -> deterministic shuffle reduce
        s  += __shfl_xor(s, 16);  s  += __shfl_xor(s, 32);
        s2 += __shfl_xor(s2, 16); s2 += __shfl_xor(s2, 32);
        if (l < 16) {
            l2s[wv*64 + nt*16 + l] = s;
            l2q[wv*64 + nt*16 + l] = s2;
        }
    }
    __syncthreads();
    if (tid < 64) {
        float ts = l2s[tid] + l2s[64+tid] + l2s[128+tid] + l2s[192+tid];
        float tq = l2q[tid] + l2q[64+tid] + l2q[128+tid] + l2q[192+tid];
        psum[tid*NBLK + blockIdx.x] = ts;
        psq [tid*NBLK + blockIdx.x] = tq;
    }
}

// ---------------------------------------------------------------------------
// Kernel 2: reduce partials -> per-channel scale/shift (deterministic order)
// ---------------------------------------------------------------------------
__global__ __launch_bounds__(256) void bn_stats_kernel(
    const float* __restrict__ psum,
    const float* __restrict__ psq,
    const float* __restrict__ gamma,
    const float* __restrict__ beta,
    float* __restrict__ ss)       // [0..63]=scale, [64..127]=shift
{
    __shared__ float rs[256], rq[256];
    const int ch = blockIdx.x, tid = threadIdx.x;
    float s = 0.f, s2 = 0.f;
    for (int j = tid; j < NBLK; j += 256) {
        s  += psum[ch*NBLK + j];
        s2 += psq [ch*NBLK + j];
    }
    rs[tid] = s; rq[tid] = s2;
    __syncthreads();
    for (int st = 128; st > 0; st >>= 1) {
        if (tid < st) { rs[tid] += rs[tid + st]; rq[tid] += rq[tid + st]; }
        __syncthreads();
    }
    if (tid == 0) {
        const float N = (float)NPIX;
        float mean = rs[0] / N;
        float var  = rq[0] / N - mean*mean;
        float rstd = rsqrtf(var + 1e-5f);
        float sc   = gamma[ch] * rstd;
        ss[ch]      = sc;
        ss[64 + ch] = beta[ch] - mean * sc;
    }
}

// ---------------------------------------------------------------------------
// Kernel 3a (bf16 path): read y bf16 from ws, affine + SiLU, write fp32 out
// ---------------------------------------------------------------------------
__global__ __launch_bounds__(256) void bn_silu_bf16_kernel(
    const unsigned short* __restrict__ yws,
    float* __restrict__ out,
    const float* __restrict__ ss)
{
    __shared__ float sc[64], sh[64];
    if (threadIdx.x < 64) {
        sc[threadIdx.x] = ss[threadIdx.x];
        sh[threadIdx.x] = ss[64 + threadIdx.x];
    }
    __syncthreads();
    const int total8 = (int)(YTOT / 8);   // 8,388,608 granules of 8 elems
    for (int i = blockIdx.x*256 + threadIdx.x; i < total8; i += gridDim.x*256) {
        us8 v = *(const us8*)(yws + (size_t)i*8);
        const int o = (i >> 13) & 63;     // (i*8)>>16 & 63
        const float a = sc[o], t = sh[o];
        float e[8];
        #pragma unroll
        for (int j = 0; j < 8; ++j) {
            float z = fmaf(bf2f(v[j]), a, t);
            e[j] = z / (1.f + __expf(-z));
        }
        float4 r0 = { e[0], e[1], e[2], e[3] };
        float4 r1 = { e[4], e[5], e[6], e[7] };
        *(float4*)(out + (size_t)i*8)     = r0;
        *(float4*)(out + (size_t)i*8 + 4) = r1;
    }
}

// ---------------------------------------------------------------------------
// Kernel 3b (fallback): in-place affine + SiLU over fp32 d_out
// ---------------------------------------------------------------------------
__global__ __launch_bounds__(256) void bn_silu_kernel(
    float* __restrict__ y,
    const float* __restrict__ ss)
{
    __shared__ float sc[64], sh[64];
    if (threadIdx.x < 64) {
        sc[threadIdx.x] = ss[threadIdx.x];
        sh[threadIdx.x] = ss[64 + threadIdx.x];
    }
    __syncthreads();
    float4* y4 = (float4*)y;
    const int total4 = (int)(YTOT / 4);
    for (int i = blockIdx.x*256 + threadIdx.x; i < total4; i += gridDim.x*256) {
        float4 v = y4[i];
        const int o = (i >> 14) & 63;
        const float a = sc[o], t = sh[o];
        float z;
        z = fmaf(v.x, a, t); v.x = z / (1.f + __expf(-z));
        z = fmaf(v.y, a, t); v.y = z / (1.f + __expf(-z));
        z = fmaf(v.z, a, t); v.z = z / (1.f + __expf(-z));
        z = fmaf(v.w, a, t); v.w = z / (1.f + __expf(-z));
        y4[i] = v;
    }
}

// ---------------------------------------------------------------------------
extern "C" void kernel_launch(void* const* d_in, const int* in_sizes, int n_in,
                              void* d_out, int out_size, void* d_ws, size_t ws_size,
                              hipStream_t stream) {
    const float* x      = (const float*)d_in[0];
    const float* w_off  = (const float*)d_in[1];
    const float* b_off  = (const float*)d_in[2];
    const float* w_dcn  = (const float*)d_in[3];
    const float* w_conv = (const float*)d_in[4];
    const float* b_conv = (const float*)d_in[5];
    const float* gamma  = (const float*)d_in[6];
    const float* beta   = (const float*)d_in[7];
    float* out = (float*)d_out;

    const size_t ybytes    = YTOT * 2;                       // 128 MiB bf16 y
    const size_t statbytes = 2*(size_t)64*NBLK*4 + 512;

    if (ws_size >= ybytes + statbytes) {
        // bf16 intermediate path: K1 writes 128 MB, K3 reads 128 + writes 256
        unsigned short* yws = (unsigned short*)d_ws;
        float* psum = (float*)((char*)d_ws + ybytes);        // 64*NBLK
        float* psq  = psum + 64*NBLK;
        float* ss   = psq  + 64*NBLK;
        dcn_fused_kernel<true><<<NBLK, 256, 0, stream>>>(
            x, w_off, b_off, w_dcn, w_conv, b_conv, out, yws, psum, psq);
        bn_stats_kernel<<<64, 256, 0, stream>>>(psum, psq, gamma, beta, ss);
        bn_silu_bf16_kernel<<<2048, 256, 0, stream>>>(yws, out, ss);
    } else {
        // fallback: fp32 y staged in d_out, normalized in place
        float* psum = (float*)d_ws;
        float* psq  = psum + 64*NBLK;
        float* ss   = psq  + 64*NBLK;
        dcn_fused_kernel<false><<<NBLK, 256, 0, stream>>>(
            x, w_off, b_off, w_dcn, w_conv, b_conv, out, nullptr, psum, psq);
        bn_stats_kernel<<<64, 256, 0, stream>>>(psum, psq, gamma, beta, ss);
        bn_silu_kernel<<<2048, 256, 0, stream>>>(out, ss);
    }
}

// Round 4
// 222.512 us; speedup vs baseline: 1.4170x; 1.0560x over previous
//
#include <hip/hip_runtime.h>
#include <hip/hip_bf16.h>
#include <math.h>

#define BB 16
#define COUTC 64
#define HH 256
#define WWD 256
#define NBLK (BB*HH)          // 4096 blocks for kernel1
#define NPIX (BB*HH*WWD)      // 1,048,576 pixels
#define YTOT ((size_t)NPIX*COUTC)   // 67,108,864 y elements

typedef __attribute__((ext_vector_type(8))) short short8;
typedef __attribute__((ext_vector_type(4))) float f32x4;
typedef __attribute__((ext_vector_type(4))) unsigned short us4;
typedef __attribute__((ext_vector_type(8))) unsigned short us8;

__device__ __forceinline__ unsigned short f2bf(float f) {
    __hip_bfloat16 h = __float2bfloat16(f);
    return __builtin_bit_cast(unsigned short, h);
}
__device__ __forceinline__ float bf2f(unsigned short u) {
    unsigned v = (unsigned)u << 16;
    return __builtin_bit_cast(float, v);
}

// ---------------------------------------------------------------------------
// Kernel 1: offset conv + deformable sampling (fp32 VALU) + fused
// [256px x 64k] @ [64k x 64ch] matmul on MFMA (bf16 in / fp32 accum).
// K-layout: k 0..26 = xn (pairs w_conv), 27..31 = 0, k 32..58 = taps
// (pairs w_dcn), 59..63 = 0 — clean 32-k halves so xn dies before taps.
// Liveness-staged + sequential nt-tiles => VGPR <= 128 (forced by
// __launch_bounds__(256,4)) => 4 blocks/CU with 40KB LDS, 50% occupancy.
// ---------------------------------------------------------------------------
template<bool BF16Y>
__global__ __launch_bounds__(256, 4) void dcn_fused_kernel(
    const float* __restrict__ x,
    const float* __restrict__ w_off,
    const float* __restrict__ b_off,
    const float* __restrict__ w_dcn,
    const float* __restrict__ w_conv,
    const float* __restrict__ b_conv,
    float* __restrict__ outf,
    unsigned short* __restrict__ yws,
    float* __restrict__ psum,     // [64][NBLK]
    float* __restrict__ psq)      // [64][NBLK]
{
    // LDS (40960 B -> 4 blocks/CU):
    //   [0,32768)      kbuf: A bf16 [256px][64k], 128B rows, 16B-chunk XOR
    //                  swizzle (chunk ^= px&7). Reused (after barrier2) as
    //                  stats scratch [4wv][64ch] x2.
    //   [32768,40960)  wT: bf16 [64n][64k], same swizzle.
    __shared__ __align__(16) char smem[40960];
    char* kbp = smem;
    char* wtp = smem + 32768;

    const int tid = threadIdx.x;
    // XCD-bijective swizzle (4096 % 8 == 0): each XCD gets 512 contiguous
    // (b,h) rows = 2 full images' x in its L2.
    const int bid = blockIdx.x;
    const int swz = (bid & 7) * 512 + (bid >> 3);
    const int b = swz >> 8;
    const int h = swz & 255;
    const int w = tid;
    const int l   = tid & 63;     // lane
    const int wv  = tid >> 6;     // wave 0..3 (owns px 64*wv..64*wv+63)
    const int g   = l >> 4;       // lane group 0..3
    const int r15 = l & 15;

    const float* xb = x + (size_t)b * (3*HH*WWD);

    // --- 3x3 zero-padded neighborhood, 3 channels (issue loads early) -----
    float xn[3][3][3];
    #pragma unroll
    for (int c = 0; c < 3; ++c) {
        #pragma unroll
        for (int dy = 0; dy < 3; ++dy) {
            int yy = h + dy - 1;
            #pragma unroll
            for (int dx = 0; dx < 3; ++dx) {
                int xx = w + dx - 1;
                bool ok = (yy >= 0) && (yy < HH) && (xx >= 0) && (xx < WWD);
                xn[c][dy][dx] = ok ? xb[c*(HH*WWD) + yy*WWD + xx] : 0.f;
            }
        }
    }

    // --- build wT[n][k] bf16 (w_conv k0..26 | w_dcn k32..58), swizzled ----
    {
        const int n = tid >> 2, kb0 = (tid & 3) * 16;
        unsigned short tmp[16];
        #pragma unroll
        for (int j = 0; j < 16; ++j) {
            int k = kb0 + j;
            float v = 0.f;
            if (k < 27)                  v = w_conv[n*27 + k];
            else if (k >= 32 && k < 59)  v = w_dcn[n*27 + (k - 32)];
            tmp[j] = f2bf(v);
        }
        #pragma unroll
        for (int c = 0; c < 2; ++c) {
            int chunk = (kb0 >> 3) + c;
            uint4 v;
            v.x = (unsigned)tmp[c*8+0] | ((unsigned)tmp[c*8+1] << 16);
            v.y = (unsigned)tmp[c*8+2] | ((unsigned)tmp[c*8+3] << 16);
            v.z = (unsigned)tmp[c*8+4] | ((unsigned)tmp[c*8+5] << 16);
            v.w = (unsigned)tmp[c*8+6] | ((unsigned)tmp[c*8+7] << 16);
            *(uint4*)(wtp + n*128 + ((chunk ^ (n & 7)) << 4)) = v;
        }
    }

    // --- offset conv: 18 channels (weights wave-uniform -> s_load) --------
    float off[18];
    #pragma unroll
    for (int j = 0; j < 18; ++j) off[j] = b_off[j];
    #pragma unroll
    for (int c = 0; c < 3; ++c)
        #pragma unroll
        for (int ky = 0; ky < 3; ++ky)
            #pragma unroll
            for (int kx = 0; kx < 3; ++kx) {
                float v = xn[c][ky][kx];
                #pragma unroll
                for (int j = 0; j < 18; ++j)
                    off[j] = fmaf(v, w_off[((j*3 + c)*3 + ky)*3 + kx], off[j]);
            }

    // --- pack xn half (chunks 0..3) now -> xn registers die here ----------
    {
        unsigned short u[32];
        #pragma unroll
        for (int c = 0; c < 3; ++c)
            #pragma unroll
            for (int ky = 0; ky < 3; ++ky)
                #pragma unroll
                for (int kx = 0; kx < 3; ++kx)
                    u[c*9 + ky*3 + kx] = f2bf(xn[c][ky][kx]);
        #pragma unroll
        for (int k = 27; k < 32; ++k) u[k] = 0;
        #pragma unroll
        for (int c8 = 0; c8 < 4; ++c8) {
            uint4 v;
            v.x = (unsigned)u[c8*8+0] | ((unsigned)u[c8*8+1] << 16);
            v.y = (unsigned)u[c8*8+2] | ((unsigned)u[c8*8+3] << 16);
            v.z = (unsigned)u[c8*8+4] | ((unsigned)u[c8*8+5] << 16);
            v.w = (unsigned)u[c8*8+6] | ((unsigned)u[c8*8+7] << 16);
            *(uint4*)(kbp + w*128 + ((c8 ^ (w & 7)) << 4)) = v;
        }
    }

    // --- deformable bilinear taps (fp32); off dies here -------------------
    float taps[9][3];
    #pragma unroll
    for (int k = 0; k < 9; ++k) {
        const int ky = k / 3, kx = k % 3;
        float py = (float)(h + ky - 1) + off[2*k];
        float px = (float)(w + kx - 1) + off[2*k + 1];
        float y0f = floorf(py), x0f = floorf(px);
        float ly = py - y0f, lx = px - x0f;
        float hy = 1.f - ly, hx = 1.f - lx;
        int y0 = (int)y0f, x0 = (int)x0f;
        int y1 = y0 + 1,  x1 = x0 + 1;
        bool vy0 = (y0 >= 0) && (y0 < HH);
        bool vy1 = (y1 >= 0) && (y1 < HH);
        bool vx0 = (x0 >= 0) && (x0 < WWD);
        bool vx1 = (x1 >= 0) && (x1 < WWD);
        float w00 = (vy0 && vx0) ? hy*hx : 0.f;
        float w01 = (vy0 && vx1) ? hy*lx : 0.f;
        float w10 = (vy1 && vx0) ? ly*hx : 0.f;
        float w11 = (vy1 && vx1) ? ly*lx : 0.f;
        int yc0 = min(max(y0, 0), HH-1),  yc1 = min(max(y1, 0), HH-1);
        int xc0 = min(max(x0, 0), WWD-1), xc1 = min(max(x1, 0), WWD-1);
        int i00 = yc0*WWD + xc0, i01 = yc0*WWD + xc1;
        int i10 = yc1*WWD + xc0, i11 = yc1*WWD + xc1;
        #pragma unroll
        for (int c = 0; c < 3; ++c) {
            const float* xc = xb + c*(HH*WWD);
            taps[k][c] = w00*xc[i00] + w01*xc[i01] + w10*xc[i10] + w11*xc[i11];
        }
    }

    // --- pack taps half (chunks 4..7); taps die here ----------------------
    {
        unsigned short u[32];
        #pragma unroll
        for (int c = 0; c < 3; ++c)
            #pragma unroll
            for (int kt = 0; kt < 9; ++kt)
                u[c*9 + kt] = f2bf(taps[kt][c]);
        #pragma unroll
        for (int k = 27; k < 32; ++k) u[k] = 0;
        #pragma unroll
        for (int c8 = 4; c8 < 8; ++c8) {
            const int j0 = (c8 - 4) * 8;
            uint4 v;
            v.x = (unsigned)u[j0+0] | ((unsigned)u[j0+1] << 16);
            v.y = (unsigned)u[j0+2] | ((unsigned)u[j0+3] << 16);
            v.z = (unsigned)u[j0+4] | ((unsigned)u[j0+5] << 16);
            v.w = (unsigned)u[j0+6] | ((unsigned)u[j0+7] << 16);
            *(uint4*)(kbp + w*128 + ((c8 ^ (w & 7)) << 4)) = v;
        }
    }

    __syncthreads();   // barrier1: staging complete

    // --- hoist all A-fragments (32 VGPR), then free kbuf for scratch ------
    short8 a[2][4];
    #pragma unroll
    for (int ks = 0; ks < 2; ++ks)
        #pragma unroll
        for (int mt = 0; mt < 4; ++mt) {
            int row = wv*64 + mt*16 + r15;
            int chunk = ks*4 + g;
            a[ks][mt] = *(const short8*)(kbp + row*128 + ((chunk ^ (row & 7)) << 4));
        }

    __syncthreads();   // barrier2: all kbuf reads done -> reuse as scratch

    float* l2s = (float*)kbp;           // [4wv][64ch]
    float* l2q = (float*)(kbp + 1024);  // [4wv][64ch]

    // --- sequential nt-tiles: bfr(8) + acc(16) live per tile --------------
    #pragma unroll
    for (int nt = 0; nt < 4; ++nt) {
        const int n = nt*16 + r15;
        short8 b0 = *(const short8*)(wtp + n*128 + (((0*4 + g) ^ (n & 7)) << 4));
        short8 b1 = *(const short8*)(wtp + n*128 + (((1*4 + g) ^ (n & 7)) << 4));

        f32x4 acc[4];
        #pragma unroll
        for (int mt = 0; mt < 4; ++mt)
            acc[mt] = (f32x4){0.f, 0.f, 0.f, 0.f};
        #pragma unroll
        for (int mt = 0; mt < 4; ++mt)
            acc[mt] = __builtin_amdgcn_mfma_f32_16x16x32_bf16(a[0][mt], b0, acc[mt], 0, 0, 0);
        #pragma unroll
        for (int mt = 0; mt < 4; ++mt)
            acc[mt] = __builtin_amdgcn_mfma_f32_16x16x32_bf16(a[1][mt], b1, acc[mt], 0, 0, 0);

        const float bcv = b_conv[nt*16 + r15];
        float s = 0.f, s2 = 0.f;
        // D layout: ch = nt*16 + r15, px = wv*64 + mt*16 + g*4 + reg
        const size_t base = ((size_t)(b*64 + nt*16 + r15) << 16)
                          + (size_t)h*256 + wv*64 + g*4;
        #pragma unroll
        for (int mt = 0; mt < 4; ++mt) {
            f32x4 v = acc[mt];
            float ox = v.x + bcv, oy = v.y + bcv, oz = v.z + bcv, ow = v.w + bcv;
            s += ox + oy + oz + ow;
            s2 = fmaf(ox, ox, s2); s2 = fmaf(oy, oy, s2);
            s2 = fmaf(oz, oz, s2); s2 = fmaf(ow, ow, s2);
            if (BF16Y) {
                us4 pv = { f2bf(ox), f2bf(oy), f2bf(oz), f2bf(ow) };
                *(us4*)(yws + base + mt*16) = pv;
            } else {
                float4 pv = { ox, oy, oz, ow };
                *(float4*)(outf + base + mt*16) = pv;
            }
        }
        // lanes l, l^16, l^32, l^48 share ch -> deterministic shuffle reduce
        s  += __shfl_xor(s, 16);  s  += __shfl_xor(s, 32);
        s2 += __shfl_xor(s2, 16); s2 += __shfl_xor(s2, 32);
        if (l < 16) {
            l2s[wv*64 + nt*16 + l] = s;
            l2q[wv*64 + nt*16 + l] = s2;
        }
    }
    __syncthreads();   // barrier3
    if (tid < 64) {
        float ts = l2s[tid] + l2s[64+tid] + l2s[128+tid] + l2s[192+tid];
        float tq = l2q[tid] + l2q[64+tid] + l2q[128+tid] + l2q[192+tid];
        psum[tid*NBLK + swz] = ts;
        psq [tid*NBLK + swz] = tq;
    }
}

// ---------------------------------------------------------------------------
// Kernel 2: reduce partials -> per-channel scale/shift (deterministic order)
// ---------------------------------------------------------------------------
__global__ __launch_bounds__(256) void bn_stats_kernel(
    const float* __restrict__ psum,
    const float* __restrict__ psq,
    const float* __restrict__ gamma,
    const float* __restrict__ beta,
    float* __restrict__ ss)       // [0..63]=scale, [64..127]=shift
{
    __shared__ float rs[256], rq[256];
    const int ch = blockIdx.x, tid = threadIdx.x;
    float s = 0.f, s2 = 0.f;
    for (int j = tid; j < NBLK; j += 256) {
        s  += psum[ch*NBLK + j];
        s2 += psq [ch*NBLK + j];
    }
    rs[tid] = s; rq[tid] = s2;
    __syncthreads();
    for (int st = 128; st > 0; st >>= 1) {
        if (tid < st) { rs[tid] += rs[tid + st]; rq[tid] += rq[tid + st]; }
        __syncthreads();
    }
    if (tid == 0) {
        const float N = (float)NPIX;
        float mean = rs[0] / N;
        float var  = rq[0] / N - mean*mean;
        float rstd = rsqrtf(var + 1e-5f);
        float sc   = gamma[ch] * rstd;
        ss[ch]      = sc;
        ss[64 + ch] = beta[ch] - mean * sc;
    }
}

// ---------------------------------------------------------------------------
// Kernel 3a (bf16 path): read y bf16 from ws, affine + SiLU, write fp32 out
// ---------------------------------------------------------------------------
__global__ __launch_bounds__(256) void bn_silu_bf16_kernel(
    const unsigned short* __restrict__ yws,
    float* __restrict__ out,
    const float* __restrict__ ss)
{
    __shared__ float sc[64], sh[64];
    if (threadIdx.x < 64) {
        sc[threadIdx.x] = ss[threadIdx.x];
        sh[threadIdx.x] = ss[64 + threadIdx.x];
    }
    __syncthreads();
    const int total8 = (int)(YTOT / 8);   // 8,388,608 granules of 8 elems
    for (int i = blockIdx.x*256 + threadIdx.x; i < total8; i += gridDim.x*256) {
        us8 v = *(const us8*)(yws + (size_t)i*8);
        const int o = (i >> 13) & 63;     // (i*8)>>16 & 63
        const float a = sc[o], t = sh[o];
        float e[8];
        #pragma unroll
        for (int j = 0; j < 8; ++j) {
            float z = fmaf(bf2f(v[j]), a, t);
            e[j] = z / (1.f + __expf(-z));
        }
        float4 r0 = { e[0], e[1], e[2], e[3] };
        float4 r1 = { e[4], e[5], e[6], e[7] };
        *(float4*)(out + (size_t)i*8)     = r0;
        *(float4*)(out + (size_t)i*8 + 4) = r1;
    }
}

// ---------------------------------------------------------------------------
// Kernel 3b (fallback): in-place affine + SiLU over fp32 d_out
// ---------------------------------------------------------------------------
__global__ __launch_bounds__(256) void bn_silu_kernel(
    float* __restrict__ y,
    const float* __restrict__ ss)
{
    __shared__ float sc[64], sh[64];
    if (threadIdx.x < 64) {
        sc[threadIdx.x] = ss[threadIdx.x];
        sh[threadIdx.x] = ss[64 + threadIdx.x];
    }
    __syncthreads();
    float4* y4 = (float4*)y;
    const int total4 = (int)(YTOT / 4);
    for (int i = blockIdx.x*256 + threadIdx.x; i < total4; i += gridDim.x*256) {
        float4 v = y4[i];
        const int o = (i >> 14) & 63;
        const float a = sc[o], t = sh[o];
        float z;
        z = fmaf(v.x, a, t); v.x = z / (1.f + __expf(-z));
        z = fmaf(v.y, a, t); v.y = z / (1.f + __expf(-z));
        z = fmaf(v.z, a, t); v.z = z / (1.f + __expf(-z));
        z = fmaf(v.w, a, t); v.w = z / (1.f + __expf(-z));
        y4[i] = v;
    }
}

// ---------------------------------------------------------------------------
extern "C" void kernel_launch(void* const* d_in, const int* in_sizes, int n_in,
                              void* d_out, int out_size, void* d_ws, size_t ws_size,
                              hipStream_t stream) {
    const float* x      = (const float*)d_in[0];
    const float* w_off  = (const float*)d_in[1];
    const float* b_off  = (const float*)d_in[2];
    const float* w_dcn  = (const float*)d_in[3];
    const float* w_conv = (const float*)d_in[4];
    const float* b_conv = (const float*)d_in[5];
    const float* gamma  = (const float*)d_in[6];
    const float* beta   = (const float*)d_in[7];
    float* out = (float*)d_out;

    const size_t ybytes    = YTOT * 2;                       // 128 MiB bf16 y
    const size_t statbytes = 2*(size_t)64*NBLK*4 + 512;

    if (ws_size >= ybytes + statbytes) {
        // bf16 intermediate path: K1 writes 128 MB, K3 reads 128 + writes 256
        unsigned short* yws = (unsigned short*)d_ws;
        float* psum = (float*)((char*)d_ws + ybytes);        // 64*NBLK
        float* psq  = psum + 64*NBLK;
        float* ss   = psq  + 64*NBLK;
        dcn_fused_kernel<true><<<NBLK, 256, 0, stream>>>(
            x, w_off, b_off, w_dcn, w_conv, b_conv, out, yws, psum, psq);
        bn_stats_kernel<<<64, 256, 0, stream>>>(psum, psq, gamma, beta, ss);
        bn_silu_bf16_kernel<<<2048, 256, 0, stream>>>(yws, out, ss);
    } else {
        // fallback: fp32 y staged in d_out, normalized in place
        float* psum = (float*)d_ws;
        float* psq  = psum + 64*NBLK;
        float* ss   = psq  + 64*NBLK;
        dcn_fused_kernel<false><<<NBLK, 256, 0, stream>>>(
            x, w_off, b_off, w_dcn, w_conv, b_conv, out, nullptr, psum, psq);
        bn_stats_kernel<<<64, 256, 0, stream>>>(psum, psq, gamma, beta, ss);
        bn_silu_kernel<<<2048, 256, 0, stream>>>(out, ss);
    }
}